// Round 1
// baseline (76.682 us; speedup 1.0000x reference)
//
#include <hip/hip_runtime.h>
#include <stdint.h>

typedef float  f32x4 __attribute__((ext_vector_type(4)));
typedef short  s16x8 __attribute__((ext_vector_type(8)));
typedef short  s16x4 __attribute__((ext_vector_type(4)));
typedef unsigned int uint32;

#define B_ 16
#define N_ 256
#define T_ 64
#define F_ 128
#define KT 32
#define NT 8   /* K tiles: 8*32 = 256 */

// LDS layout (bytes). 16x16 bf16 subtiles (512B), inter-subtile stride 544
// to spread banks. X region holds ALL 8 k-tiles (residual source).
#define BLKSTR 544
#define X_TILE_STR (16 * BLKSTR)          /* 16 subtiles per X k-tile */
#define X_OFF 0
#define W_OFF (NT * X_TILE_STR)           /* 69632 */
#define E_OFF (W_OFF + 32 * BLKSTR)       /* 87040 */
#define J_OFF (E_OFF + N_ * 4)            /* 88064 */
#define LDS_SZ (J_OFF + N_)               /* 88320 */

#define TRREAD(dst, addr) \
  asm volatile("ds_read_b64_tr_b16 %0, %1" : "=v"(dst) : "v"(addr))

#define LGKM_FENCE() asm volatile("s_waitcnt lgkmcnt(0)" ::: "memory")
#define BAR()                                    \
  do {                                           \
    LGKM_FENCE();                                \
    __builtin_amdgcn_s_barrier();                \
    asm volatile("" ::: "memory");               \
  } while (0)

__device__ __forceinline__ unsigned short f2bf(float f) {
  union { float f; unsigned int u; } v; v.f = f;
  unsigned int u = v.u;
  return (unsigned short)((u + 0x7fffu + ((u >> 16) & 1u)) >> 16);
}
__device__ __forceinline__ float bf2f(unsigned short h) {
  union { unsigned int u; float f; } v; v.u = ((unsigned int)h) << 16;
  return v.f;
}

// fwTb[c][l] = bf16(full_weight[l][c])  (256x256, lives in d_ws, L2-resident)
__global__ void wtrans_kernel(const float* __restrict__ fw,
                              unsigned short* __restrict__ fwTb) {
  int c = blockIdx.x;
  int l = threadIdx.x;
  fwTb[c * N_ + l] = f2bf(fw[l * N_ + c]);
}

__global__ __launch_bounds__(512, 2) void fused_kernel(
    const float* __restrict__ x,
    const int* __restrict__ entry,
    const int* __restrict__ job,
    const unsigned short* __restrict__ fwTb,
    float* __restrict__ out) {
  __shared__ __align__(16) char smem[LDS_SZ];
  const uint32 lds_u = (uint32)(uintptr_t)(&smem[0]);

  const int tid = threadIdx.x;
  const int bid = blockIdx.x;
  const int b = bid >> 6;
  const int t = bid & 63;

  // ---- prologue: stage entry ids (i32) and job ids (u8) for all k ----
  if (tid < N_) {
    int idx = (b * N_ + tid) * T_ + t;
    *(int*)(smem + E_OFF + 4 * tid) = entry[idx];
    smem[J_OFF + tid] = (char)job[idx];
  }

  // X staging thread mapping: lane-contig in f for coalesced HBM reads
  const int xk  = tid >> 4;          // 0..31 (k offset within tile)
  const int xf0 = (tid & 15) << 3;   // 0,8,...,120

  // stage X tile 0 (f32 -> bf16, into [k16][f16] subtiles)
  {
    const float* src = x + ((b * N_ + xk) * T_ + t) * F_ + xf0;
    f32x4 r0 = *(const f32x4*)(src);
    f32x4 r1 = *(const f32x4*)(src + 4);
    s16x8 pk;
#pragma unroll
    for (int i = 0; i < 4; ++i) {
      pk[i]     = (short)f2bf(r0[i]);
      pk[i + 4] = (short)f2bf(r1[i]);
    }
    char* dst = smem + X_OFF +
                (((xk >> 4) * 8 + (xf0 >> 4)) * BLKSTR) +
                ((xk & 15) * 32) + ((xf0 & 15) * 2);
    *(s16x8*)dst = pk;
  }
  BAR();

  const int lane = tid & 63;
  const int wid  = tid >> 6;
  const int wl   = wid & 3;   // wave's 64-l tile
  const int wf   = wid >> 2;  // wave's 64-f tile

  f32x4 acc[4][4];
#pragma unroll
  for (int i = 0; i < 4; ++i)
#pragma unroll
    for (int j = 0; j < 4; ++j) acc[i][j] = (f32x4){0.f, 0.f, 0.f, 0.f};

  for (int kt = 0; kt < NT; ++kt) {
    // ---- W build (tile kt): Wm[l,k] = fwTb[e_k][l] * (j_l==j_k!=0) ----
    {
      const int wk  = tid & 31;   // k offset in tile
      const int wlg = tid >> 5;   // 0..15 l-block
      const int k   = kt * KT + wk;
      const int ev  = *(const int*)(smem + E_OFF + 4 * k);
      const unsigned char jk = (unsigned char)smem[J_OFF + k];
      const unsigned short* wrow = fwTb + ev * N_;
      const uint32 kin = (uint32)((wk & 15) * 32);
      const int kb = (wk >> 4) & 1;
#pragma unroll
      for (int it = 0; it < 2; ++it) {
        const int l0 = wlg * 16 + it * 8;
        s16x8 wv = *(const s16x8*)(wrow + l0);                 // 16B from L2
        uint64_t jl8 = *(const uint64_t*)(smem + J_OFF + l0);  // 8 job bytes
        s16x8 m;
#pragma unroll
        for (int i = 0; i < 8; ++i) {
          unsigned char jl = (unsigned char)(jl8 >> (8 * i));
          m[i] = (jk != 0 && jl == jk) ? wv[i] : (short)0;
        }
        char* dst = smem + W_OFF + ((kb * 16 + wlg) * BLKSTR) + kin + it * 16;
        *(s16x8*)dst = m;
      }
    }

    // ---- issue X global loads for tile kt+1 (stay in flight over barrier) --
    f32x4 p0, p1;
    if (kt + 1 < NT) {
      const float* src = x + ((b * N_ + (kt + 1) * KT + xk) * T_ + t) * F_ + xf0;
      p0 = *(const f32x4*)(src);
      p1 = *(const f32x4*)(src + 4);
    }

    BAR();  // lgkm-only drain: W tile visible; X loads still in flight

    // ---- MFMA: 64l x 64f per wave, K=32 ----
    {
      s16x4 ah[4][2], bh[4][2];
      const uint32 wbase = lds_u + W_OFF + (uint32)(lane * 8);
      const uint32 xbase = lds_u + X_OFF + (uint32)(kt * X_TILE_STR + lane * 8);
#pragma unroll
      for (int li = 0; li < 4; ++li) {
        const uint32 a0 = wbase + (uint32)(((0 * 16) + (wl * 4 + li)) * BLKSTR);
        const uint32 a1 = wbase + (uint32)(((1 * 16) + (wl * 4 + li)) * BLKSTR);
        TRREAD(ah[li][0], a0);
        TRREAD(ah[li][1], a1);
      }
#pragma unroll
      for (int fi = 0; fi < 4; ++fi) {
        const uint32 b0 = xbase + (uint32)(((0 * 8) + (wf * 4 + fi)) * BLKSTR);
        const uint32 b1 = xbase + (uint32)(((1 * 8) + (wf * 4 + fi)) * BLKSTR);
        TRREAD(bh[fi][0], b0);
        TRREAD(bh[fi][1], b1);
      }
      LGKM_FENCE();
      __builtin_amdgcn_sched_barrier(0);  // rule #18: keep MFMAs below the wait
#pragma unroll
      for (int li = 0; li < 4; ++li) {
        s16x8 af = __builtin_shufflevector(ah[li][0], ah[li][1],
                                           0, 1, 2, 3, 4, 5, 6, 7);
#pragma unroll
        for (int fi = 0; fi < 4; ++fi) {
          s16x8 bf = __builtin_shufflevector(bh[fi][0], bh[fi][1],
                                             0, 1, 2, 3, 4, 5, 6, 7);
          acc[li][fi] =
              __builtin_amdgcn_mfma_f32_16x16x32_bf16(af, bf, acc[li][fi], 0, 0, 0);
        }
      }
    }

    // ---- convert+write X tile kt+1 (vmcnt wait lands here, after MFMA) ----
    if (kt + 1 < NT) {
      s16x8 pk;
#pragma unroll
      for (int i = 0; i < 4; ++i) {
        pk[i]     = (short)f2bf(p0[i]);
        pk[i + 4] = (short)f2bf(p1[i]);
      }
      char* dst = smem + X_OFF + (kt + 1) * X_TILE_STR +
                  (((xk >> 4) * 8 + (xf0 >> 4)) * BLKSTR) +
                  ((xk & 15) * 32) + ((xf0 & 15) * 2);
      *(s16x8*)dst = pk;
    }

    BAR();  // X tile kt+1 visible; W buffer free for reuse
  }

  // ---- epilogue: out = x + relu(y); residual x comes from staged X LDS ----
  const int g4   = (lane >> 4) * 4;
  const int fcol = lane & 15;
#pragma unroll
  for (int li = 0; li < 4; ++li) {
    const int Lb = wl * 4 + li;  // l-block 0..15 == k-block of residual
    const uint32 rb = lds_u + X_OFF + (uint32)((Lb >> 1) * X_TILE_STR +
                       ((Lb & 1) * 8) * BLKSTR + lane * 8);
    s16x4 xr[4];
#pragma unroll
    for (int fi = 0; fi < 4; ++fi) {
      TRREAD(xr[fi], rb + (uint32)((wf * 4 + fi) * BLKSTR));
    }
    LGKM_FENCE();
    __builtin_amdgcn_sched_barrier(0);
    const int l0 = Lb * 16 + g4;
#pragma unroll
    for (int fi = 0; fi < 4; ++fi) {
      const int f = (wf * 4 + fi) * 16 + fcol;
      float* op = out + ((b * N_ + l0) * T_ + t) * F_ + f;
#pragma unroll
      for (int r = 0; r < 4; ++r) {
        float y = acc[li][fi][r];
        y = y > 0.f ? y : 0.f;
        op[r * (T_ * F_)] = bf2f((unsigned short)xr[fi][r]) + y;
      }
    }
  }
}

extern "C" void kernel_launch(void* const* d_in, const int* in_sizes, int n_in,
                              void* d_out, int out_size, void* d_ws,
                              size_t ws_size, hipStream_t stream) {
  (void)in_sizes; (void)n_in; (void)out_size; (void)ws_size;
  const float* x     = (const float*)d_in[0];
  const int*   entry = (const int*)d_in[1];
  const int*   job   = (const int*)d_in[2];
  // d_in[3] rackid unused; d_in[5..7] bias/gamma/beta dead in reference math
  const float* fw    = (const float*)d_in[4];
  unsigned short* fwTb = (unsigned short*)d_ws;  // 128 KB scratch

  hipLaunchKernelGGL(wtrans_kernel, dim3(N_), dim3(N_), 0, stream, fw, fwTb);
  hipLaunchKernelGGL(fused_kernel, dim3(B_ * T_), dim3(512), 0, stream,
                     x, entry, job, (const unsigned short*)fwTb, (float*)d_out);
}